// Round 1
// baseline (1798.349 us; speedup 1.0000x reference)
//
#include <hip/hip_runtime.h>
#include <math.h>

#define C1F 1.0e-4f   // 0.01^2
#define C2F 9.0e-4f   // 0.03^2
#define TX 32
#define TY 8
#define NSTAGE ((TY + 2) * (TX + 2))

// acc layout: per scale i (0..3), base = i*8
//  +0: sum |left_est - lpy|      +1: sum |right_est - rpy|
//  +2: sum |rl_disp - dl|        +3: sum |lr_disp - dr|
//  +4: sum x-grad smooth (dl+dr) +5: sum y-grad smooth (dl+dr)
//  +6: sum ssim_l (clipped)      +7: sum ssim_r
// acc[64] (as unsigned): completion ticket for fused finale.

struct ScaleArgs {
    const float* disp;   // scale-resolution disparity (input)
    const float* lp;     // FULL-RES left image (all scales)
    const float* rp;     // FULL-RES right image
    int h, w, nx, ny, blk0, accoff, ntiles;
    int Wf, Hf;          // full-res dims
    float syf, sxf;      // (Hf-1)/(h-1), (Wf-1)/(w-1)  (unused for scale 0)
};

__device__ __forceinline__ float2 f2(float v) { return make_float2(v, v); }
__device__ __forceinline__ float2 f2abs(float2 a) {
    return make_float2(fabsf(a.x), fabsf(a.y));
}

__device__ __forceinline__ void warp_coeffs(float px, int W, int& i0, int& i1,
                                            float& w0, float& w1) {
    float x0f = floorf(px);
    float f = px - x0f;
    int x0i = (int)x0f;
    int x1i = x0i + 1;
    float v0 = (x0i >= 0 && x0i < W) ? 1.f : 0.f;
    float v1 = (x1i >= 0 && x1i < W) ? 1.f : 0.f;
    i0 = min(max(x0i, 0), W - 1);
    i1 = min(max(x1i, 0), W - 1);
    w0 = v0 * (1.f - f);
    w1 = v1 * f;
}

template<int N>
__device__ __forceinline__ void block_acc(const float* vals, float* gacc) {
    __shared__ float sacc[N];
    if (threadIdx.x < N) sacc[threadIdx.x] = 0.f;
    __syncthreads();
#pragma unroll
    for (int k = 0; k < N; ++k) {
        float v = vals[k];
#pragma unroll
        for (int off = 32; off > 0; off >>= 1) v += __shfl_down(v, off, 64);
        if ((threadIdx.x & 63) == 0) atomicAdd(&sacc[k], v);
    }
    __syncthreads();
    if (threadIdx.x < N) atomicAdd(&gacc[threadIdx.x], sacc[threadIdx.x]);
}

// Bijective XCD-chunked swizzle (m204 form): blocks dispatched round-robin over
// 8 XCDs; remap so each XCD owns a CONTIGUOUS run of tiles -> x-neighbor tiles
// (which share warp-gather stripes + halo rows) hit the same XCD's L2.
__device__ __forceinline__ int xcd_swz(int orig, int n) {
    int q = n >> 3, r = n & 7;
    int x = orig & 7;
    int base = (x < r) ? x * (q + 1) : r * (q + 1) + (x - r) * q;
    return base + (orig >> 3);
}

__global__ void k_zero(float* acc) {
    acc[threadIdx.x] = 0.f;   // launched with 128 threads: zeroes acc + ticket
}

// ---- fused loss tile. RS=false: scale 0, stage directly from full-res images
// (phase-split for max outstanding loads). RS=true: scales 1-3, staging does
// the bilinear pyramid resample ON THE FLY (exact same formula/order as the
// old resize kernel), so no pyramid buffers and no inter-kernel dependency. ----
template<bool RS>
__device__ __forceinline__ void fused_tile(const ScaleArgs& sa, int t,
                                           float* __restrict__ accbase,
                                           float4 (*__restrict__ simg)[NSTAGE],
                                           float2* __restrict__ sdisp) {
    const int h = sa.h, w = sa.w;
    float* acc = accbase + sa.accoff;

    const int tileX = t % sa.nx;
    int t2 = t / sa.nx;
    const int tileY = t2 % sa.ny;
    const int b = t2 / sa.ny;

    const int xo0 = tileX * TX;
    const int yo0 = tileY * TY;
    const int tid = threadIdx.x;
    const float Wm1 = (float)(w - 1);
    const float invWm1 = 1.f / Wm1;
    const int chs = h * w;               // scale-res plane (disp; images if !RS)

    const float* __restrict__ dl_base = sa.disp + (b * 2 + 0) * chs;
    const float* __restrict__ dr_base = sa.disp + (b * 2 + 1) * chs;

    const int nk = (tid + 256 < NSTAGE) ? 2 : 1;

    if (!RS) {
        const float* __restrict__ limg = sa.lp + b * 3 * chs;
        const float* __restrict__ rimg = sa.rp + b * 3 * chs;
        // ---- staging: 2 slots/thread, phase-split so all loads are in flight ----
        int xs[2], ys[2];
        float dlv[2], drv[2];
#pragma unroll
        for (int k = 0; k < 2; ++k) {
            if (k < nk) {
                int i = tid + k * 256;
                int sx = i % (TX + 2);
                int sy = i / (TX + 2);
                int x = min(max(xo0 - 1 + sx, 0), w - 1);
                int y = min(max(yo0 - 1 + sy, 0), h - 1);
                xs[k] = x; ys[k] = y;
                int off = y * w + x;
                dlv[k] = dl_base[off];
                drv[k] = dr_base[off];
            }
        }
        int i0L[2], i1L[2], i0R[2], i1R[2];
        float w0L[2], w1L[2], w0R[2], w1R[2];
        float lvv[2][3], rvv[2][3], gr0[2][3], gr1[2][3], gl0[2][3], gl1[2][3];
#pragma unroll
        for (int k = 0; k < 2; ++k) {
            if (k < nk) {
                float xb = (float)xs[k] * invWm1;
                warp_coeffs((xb - dlv[k]) * Wm1, w, i0L[k], i1L[k], w0L[k], w1L[k]);
                warp_coeffs((xb + drv[k]) * Wm1, w, i0R[k], i1R[k], w0R[k], w1R[k]);
                int rowoff = ys[k] * w;
#pragma unroll
                for (int c = 0; c < 3; ++c) {
                    int co = c * chs + rowoff;
                    lvv[k][c] = limg[co + xs[k]];
                    rvv[k][c] = rimg[co + xs[k]];
                    gr0[k][c] = rimg[co + i0L[k]];
                    gr1[k][c] = rimg[co + i1L[k]];
                    gl0[k][c] = limg[co + i0R[k]];
                    gl1[k][c] = limg[co + i1R[k]];
                }
            }
        }
#pragma unroll
        for (int k = 0; k < 2; ++k) {
            if (k < nk) {
                int i = tid + k * 256;
                sdisp[i] = make_float2(dlv[k], drv[k]);
#pragma unroll
                for (int c = 0; c < 3; ++c) {
                    float le = gr0[k][c] * w0L[k] + gr1[k][c] * w1L[k];
                    float re = gl0[k][c] * w0R[k] + gl1[k][c] * w1R[k];
                    simg[c][i] = make_float4(le, re, lvv[k][c], rvv[k][c]);
                }
            }
        }
    } else {
        // ---- staging with on-the-fly bilinear resample from full-res ----
        const int Wf = sa.Wf;
        const int chsF = sa.Hf * Wf;
        const float* __restrict__ limgF = sa.lp + b * 3 * chsF;
        const float* __restrict__ rimgF = sa.rp + b * 3 * chsF;
        for (int k = 0; k < nk; ++k) {
            int i = tid + (k << 8);
            int sx = i % (TX + 2);
            int sy = i / (TX + 2);
            int x = min(max(xo0 - 1 + sx, 0), w - 1);
            int y = min(max(yo0 - 1 + sy, 0), h - 1);
            int off = y * w + x;
            float dlv = dl_base[off];
            float drv = dr_base[off];
            // y interp (shared by all 5 x-positions; exact old-resize formula)
            float fy = (float)y * sa.syf;
            int y0 = (int)floorf(fy);
            float wy = fy - (float)y0;
            int y1 = min(y0 + 1, sa.Hf - 1);
            y0 = min(y0, sa.Hf - 1);
            float omwy = 1.f - wy;
            int ro0 = y0 * Wf, ro1 = y1 * Wf;
            // warp gather positions on the RESIZED grid
            float xb = (float)x * invWm1;
            int i0L, i1L, i0R, i1R;
            float w0L, w1L, w0R, w1R;
            warp_coeffs((xb - dlv) * Wm1, w, i0L, i1L, w0L, w1L);
            warp_coeffs((xb + drv) * Wm1, w, i0R, i1R, w0R, w1R);
            int px_[5] = {x, i0L, i1L, i0R, i1R};
            int x0p[5], x1p[5];
            float wxp[5];
#pragma unroll
            for (int p = 0; p < 5; ++p) {
                float fx = (float)px_[p] * sa.sxf;
                int x0 = (int)floorf(fx);
                wxp[p] = fx - (float)x0;
                x1p[p] = min(x0 + 1, Wf - 1);
                x0p[p] = min(x0, Wf - 1);
            }
            auto BIL = [&](const float* P0, const float* P1, int p) -> float {
                float r0 = P0[x0p[p]] * omwy + P1[x0p[p]] * wy;
                float r1 = P0[x1p[p]] * omwy + P1[x1p[p]] * wy;
                return r0 * (1.f - wxp[p]) + r1 * wxp[p];
            };
            sdisp[i] = make_float2(dlv, drv);
#pragma unroll
            for (int c = 0; c < 3; ++c) {
                const float* L0 = limgF + c * chsF + ro0;
                const float* L1 = limgF + c * chsF + ro1;
                const float* R0 = rimgF + c * chsF + ro0;
                const float* R1 = rimgF + c * chsF + ro1;
                float lv = BIL(L0, L1, 0);
                float rv = BIL(R0, R1, 0);
                float g0 = BIL(R0, R1, 1);
                float g1 = BIL(R0, R1, 2);
                float h0 = BIL(L0, L1, 3);
                float h1 = BIL(L0, L1, 4);
                simg[c][i] = make_float4(g0 * w0L + g1 * w1L,
                                         h0 * w0R + h1 * w1R, lv, rv);
            }
        }
    }
    __syncthreads();

    float sums[8] = {0.f, 0.f, 0.f, 0.f, 0.f, 0.f, 0.f, 0.f};
    const int tx = tid % TX, ty = tid / TX;
    const int x = xo0 + tx, y = yo0 + ty;
    if (x < w && y < h) {
        const int s = (ty + 1) * (TX + 2) + (tx + 1);
        float2 dd = sdisp[s];
        float dl = dd.x, dr = dd.y;
#pragma unroll
        for (int c = 0; c < 3; ++c) {
            float4 v = simg[c][s];
            float2 d = f2abs(make_float2(v.x, v.y) - make_float2(v.z, v.w));
            sums[0] += d.x;
            sums[1] += d.y;
        }
        // LR consistency (far gathers on disp rows -> global)
        {
            float xb = (float)x * invWm1;
            int i0, i1; float w0, w1;
            warp_coeffs((xb - dl) * Wm1, w, i0, i1, w0, w1);
            const float* dr_row = dr_base + y * w;
            float rl = dr_row[i0] * w0 + dr_row[i1] * w1;
            sums[2] += fabsf(rl - dl);
            warp_coeffs((xb + dr) * Wm1, w, i0, i1, w0, w1);
            const float* dl_row = dl_base + y * w;
            float lr = dl_row[i0] * w0 + dl_row[i1] * w1;
            sums[3] += fabsf(lr - dr);
        }
        const float third = 1.f / 3.f;
        if (x < w - 1) {
            float2 d1 = sdisp[s + 1];
            float2 alr = f2(0.f);
#pragma unroll
            for (int c = 0; c < 3; ++c) {
                float4 v = simg[c][s];
                float4 v1 = simg[c][s + 1];
                alr = alr + f2abs(make_float2(v.z, v.w) - make_float2(v1.z, v1.w));
            }
            sums[4] += fabsf((dl - d1.x) * __expf(-alr.x * third)) +
                       fabsf((dr - d1.y) * __expf(-alr.y * third));
        }
        if (y < h - 1) {
            float2 d1 = sdisp[s + (TX + 2)];
            float2 alr = f2(0.f);
#pragma unroll
            for (int c = 0; c < 3; ++c) {
                float4 v = simg[c][s];
                float4 v1 = simg[c][s + (TX + 2)];
                alr = alr + f2abs(make_float2(v.z, v.w) - make_float2(v1.z, v1.w));
            }
            sums[5] += fabsf((dl - d1.x) * __expf(-alr.x * third)) +
                       fabsf((dr - d1.y) * __expf(-alr.y * third));
        }
        if (x >= 1 && x <= w - 2 && y >= 1 && y <= h - 2) {
            const float2 inv9 = f2(1.f / 9.f);
            const float2 c1 = f2(C1F), c2 = f2(C2F);
            const float2 two = f2(2.f), one = f2(1.f), half_ = f2(0.5f);
#pragma unroll 1
            for (int c = 0; c < 3; ++c) {
                float2 sX = f2(0.f), sY = f2(0.f);
                float2 sXX = f2(0.f), sYY = f2(0.f), sXY = f2(0.f);
#pragma unroll
                for (int dy = 0; dy < 3; ++dy) {
#pragma unroll
                    for (int dx = 0; dx < 3; ++dx) {
                        float4 v = simg[c][(ty + dy) * (TX + 2) + (tx + dx)];
                        float2 a = make_float2(v.x, v.y);
                        float2 bb = make_float2(v.z, v.w);
                        sX = sX + a;
                        sY = sY + bb;
                        sXX = sXX + a * a;
                        sYY = sYY + bb * bb;
                        sXY = sXY + a * bb;
                    }
                }
                float2 mx = sX * inv9, my = sY * inv9;
                float2 vx = sXX * inv9 - mx * mx;
                float2 vy = sYY * inv9 - my * my;
                float2 vxy = sXY * inv9 - mx * my;
                float2 num = (two * mx * my + c1) * (two * vxy + c2);
                float2 den = (mx * mx + my * my + c1) * (vx + vy + c2);
                float2 ss = make_float2(num.x * __builtin_amdgcn_rcpf(den.x),
                                        num.y * __builtin_amdgcn_rcpf(den.y));
                float2 v = (one - ss) * half_;
                sums[6] += fminf(fmaxf(v.x, 0.f), 1.f);
                sums[7] += fminf(fmaxf(v.y, 0.f), 1.f);
            }
        }
    }
    block_acc<8>(sums, acc);
}

// ---- single kernel: all 4 scales, all blocks independent; last block folds
// the final weighted reduction (former k_final) via a device-scope ticket ----
__global__ void __launch_bounds__(256, 4)
k_main(ScaleArgs s0, ScaleArgs s1, ScaleArgs s2, ScaleArgs s3,
       float* __restrict__ accbase, float* __restrict__ out,
       int nTotal, int B, int H, int W) {
    __shared__ float4 simg[3][NSTAGE];
    __shared__ float2 sdisp[NSTAGE];

    int blk = blockIdx.x;
    if (blk < s1.blk0) {
        int t = xcd_swz(blk, s0.ntiles);
        fused_tile<false>(s0, t, accbase, simg, sdisp);
    } else {
        ScaleArgs sa = (blk >= s3.blk0) ? s3 : ((blk >= s2.blk0) ? s2 : s1);
        int t = xcd_swz(blk - sa.blk0, sa.ntiles);
        fused_tile<true>(sa, t, accbase, simg, sdisp);
    }

    __syncthreads();   // drain this block's global atomics (vmcnt(0) at barrier)
    if (threadIdx.x == 0) {
        __threadfence();
        unsigned* tic = (unsigned*)(accbase + 64);
        unsigned prev = __hip_atomic_fetch_add(tic, 1u, __ATOMIC_ACQ_REL,
                                               __HIP_MEMORY_SCOPE_AGENT);
        if (prev == (unsigned)(nTotal - 1)) {
            float a[32];
#pragma unroll 1
            for (int k = 0; k < 32; ++k)
                a[k] = __hip_atomic_load(&accbase[k], __ATOMIC_RELAXED,
                                         __HIP_MEMORY_SCOPE_AGENT);
            float img = 0.f, lr = 0.f, sm = 0.f;
#pragma unroll 1
            for (int i = 0; i < 4; ++i) {
                int r = 1 << i;
                int h = H / r, w = W / r;
                const float* ac = a + i * 8;
                float Nl1 = (float)B * 3.f * (float)h * (float)w;
                float Nss = (float)B * 3.f * (float)(h - 2) * (float)(w - 2);
                float Nlr = (float)B * (float)h * (float)w;
                float Nsx = (float)B * (float)h * (float)(w - 1);
                float Nsy = (float)B * (float)(h - 1) * (float)w;
                img += 0.5f * (ac[6] / Nss) + 0.5f * (ac[0] / Nl1)
                     + 0.5f * (ac[7] / Nss) + 0.5f * (ac[1] / Nl1);
                lr += ac[2] / Nlr + ac[3] / Nlr;
                sm += (ac[4] / Nsx + ac[5] / Nsy) / (float)r;
            }
            out[0] = img + 0.1f * sm + 1.0f * lr;
        }
    }
}

extern "C" void kernel_launch(void* const* d_in, const int* in_sizes, int n_in,
                              void* d_out, int out_size, void* d_ws, size_t ws_size,
                              hipStream_t stream) {
    const int B = 16, H = 384, W = 768;
    const float* disp[4] = {(const float*)d_in[0], (const float*)d_in[1],
                            (const float*)d_in[2], (const float*)d_in[3]};
    const float* left = (const float*)d_in[4];
    const float* right = (const float*)d_in[5];
    float* out = (float*)d_out;
    float* acc = (float*)d_ws;   // 0..31 sums, 64 = ticket

    ScaleArgs sa[4];
    int blk0 = 0;
    for (int i = 0; i < 4; ++i) {
        int r = 1 << i;
        int h = H / r, w = W / r;
        sa[i].disp = disp[i];
        sa[i].lp = left;
        sa[i].rp = right;
        sa[i].h = h;
        sa[i].w = w;
        sa[i].nx = w / TX;
        sa[i].ny = h / TY;
        sa[i].accoff = i * 8;
        sa[i].ntiles = sa[i].nx * sa[i].ny * B;
        sa[i].blk0 = blk0;
        blk0 += sa[i].ntiles;
        sa[i].Wf = W;
        sa[i].Hf = H;
        sa[i].syf = (i == 0) ? 1.f : (float)(H - 1) / (float)(h - 1);
        sa[i].sxf = (i == 0) ? 1.f : (float)(W - 1) / (float)(w - 1);
    }
    int nTotal = blk0;   // 18432 + 4608 + 1152 + 288 = 24480

    hipLaunchKernelGGL(k_zero, dim3(1), dim3(128), 0, stream, acc);
    hipLaunchKernelGGL(k_main, dim3((unsigned)nTotal), dim3(256), 0, stream,
                       sa[0], sa[1], sa[2], sa[3], acc, out, nTotal, B, H, W);
}

// Round 2
// 732.205 us; speedup vs baseline: 2.4561x; 2.4561x over previous
//
#include <hip/hip_runtime.h>
#include <math.h>

#define C1F 1.0e-4f   // 0.01^2
#define C2F 9.0e-4f   // 0.03^2
#define TX 64
#define TY 4
#define NROWS (TY + 2)                       // 6
#define NSTAGE ((TY + 2) * (TX + 2))         // 396

// acc layout: per scale i (0..3), base = i*8
//  +0: sum |left_est - lpy|      +1: sum |right_est - rpy|
//  +2: sum |rl_disp - dl|        +3: sum |lr_disp - dr|
//  +4: sum x-grad smooth (dl+dr) +5: sum y-grad smooth (dl+dr)
//  +6: sum ssim_l (clipped)      +7: sum ssim_r

struct ScaleArgs {
    const float* disp;   // scale-res disparity
    const float* lp;     // scale-res left image (pyramid for i>0)
    const float* rp;     // scale-res right image
    int h, w, nx, ny, blk0, accoff, ntiles;
    int maxd;            // max gather reach in px at this scale
    float dmax;          // maxd/(w-1): fast-path disparity bound
};

__device__ __forceinline__ float2 f2(float v) { return make_float2(v, v); }
__device__ __forceinline__ float2 f2abs(float2 a) {
    return make_float2(fabsf(a.x), fabsf(a.y));
}

__device__ __forceinline__ void warp_coeffs(float px, int W, int& i0, int& i1,
                                            float& w0, float& w1) {
    float x0f = floorf(px);
    float f = px - x0f;
    int x0i = (int)x0f;
    int x1i = x0i + 1;
    float v0 = (x0i >= 0 && x0i < W) ? 1.f : 0.f;
    float v1 = (x1i >= 0 && x1i < W) ? 1.f : 0.f;
    i0 = min(max(x0i, 0), W - 1);
    i1 = min(max(x1i, 0), W - 1);
    w0 = v0 * (1.f - f);
    w1 = v1 * f;
}

template<int N>
__device__ __forceinline__ void block_acc(const float* vals, float* gacc) {
    __shared__ float sacc[N];
    if (threadIdx.x < N) sacc[threadIdx.x] = 0.f;
    __syncthreads();
#pragma unroll
    for (int k = 0; k < N; ++k) {
        float v = vals[k];
#pragma unroll
        for (int off = 32; off > 0; off >>= 1) v += __shfl_down(v, off, 64);
        if ((threadIdx.x & 63) == 0) atomicAdd(&sacc[k], v);
    }
    __syncthreads();
    if (threadIdx.x < N) atomicAdd(&gacc[threadIdx.x], sacc[threadIdx.x]);
}

// Bijective XCD-chunked swizzle (m204 form).
__device__ __forceinline__ int xcd_swz(int orig, int n) {
    int q = n >> 3, r = n & 7;
    int x = orig & 7;
    int base = (x < r) ? x * (q + 1) : r * (q + 1) + (x - r) * q;
    return base + (orig >> 3);
}

__global__ void k_zero(float* acc) {
    if (threadIdx.x < 64) acc[threadIdx.x] = 0.f;
}

// ---- fused loss tile with LDS-staged gather stripes ----
// Stripes (coalesced staging) hold everything the random-disparity gathers
// can touch: right img / dr over [xo0-1-MAXD, +SW), left img / dl over
// [xo0-1, +SW). A per-tile uniform range check on disparity selects the
// LDS fast path; out-of-range disp falls back to global gathers (exact
// round-0 semantics), so correctness never depends on the data.
template<int SW>
__device__ void fused_tile(const ScaleArgs& sa, int t, float* __restrict__ accbase,
                           float4* __restrict__ simg,      // [3*NSTAGE] le,re,lv,rv
                           float* __restrict__ sLp,        // [3*NROWS*SW]
                           float* __restrict__ sRp,        // [3*NROWS*SW]
                           float* __restrict__ sdl,        // [NROWS*SW]
                           float* __restrict__ sdr,        // [NROWS*SW]
                           int* __restrict__ sok) {
    const int h = sa.h, w = sa.w;
    float* acc = accbase + sa.accoff;

    const int tileX = t % sa.nx;
    int t2 = t / sa.nx;
    const int tileY = t2 % sa.ny;
    const int b = t2 / sa.ny;

    const int xo0 = tileX * TX;
    const int yo0 = tileY * TY;
    const int tid = threadIdx.x;
    const float Wm1 = (float)(w - 1);
    const float invWm1 = 1.f / Wm1;
    const int chs = h * w;
    const int MAXD = sa.maxd;
    const int lx0 = xo0 - 1;
    const int rx0 = xo0 - 1 - MAXD;
    const int gy0 = yo0 - 1;

    const float* __restrict__ dl_base = sa.disp + (b * 2 + 0) * chs;
    const float* __restrict__ dr_base = sa.disp + (b * 2 + 1) * chs;
    const float* __restrict__ limg = sa.lp + b * 3 * chs;
    const float* __restrict__ rimg = sa.rp + b * 3 * chs;

    if (tid == 0) *sok = 1;
    __syncthreads();

    // ---- stage image stripes (coalesced rows) ----
    for (int i = tid; i < 6 * NROWS * SW; i += 256) {
        int k = i % SW;
        int tt = i / SW;
        int r = tt % NROWS;
        int cc = tt / NROWS;                 // 0..2 left, 3..5 right
        int y = min(max(gy0 + r, 0), h - 1);
        if (cc < 3) {
            int x = min(max(lx0 + k, 0), w - 1);
            sLp[(cc * NROWS + r) * SW + k] = limg[cc * chs + y * w + x];
        } else {
            int c = cc - 3;
            int x = min(max(rx0 + k, 0), w - 1);
            sRp[(c * NROWS + r) * SW + k] = rimg[c * chs + y * w + x];
        }
    }
    // ---- stage disparity stripes + fast-path range check ----
    bool bad = false;
    for (int i = tid; i < 2 * NROWS * SW; i += 256) {
        int k = i % SW;
        int tt = i / SW;
        int r = tt % NROWS;
        int y = min(max(gy0 + r, 0), h - 1);
        float v;
        if (tt < NROWS) {
            int x = min(max(lx0 + k, 0), w - 1);
            v = dl_base[y * w + x];
            sdl[r * SW + k] = v;
        } else {
            int x = min(max(rx0 + k, 0), w - 1);
            v = dr_base[y * w + x];
            sdr[r * SW + k] = v;
        }
        bad = bad || !(v >= 0.f && v <= sa.dmax);   // catches NaN too
    }
    if (bad) *sok = 0;
    __syncthreads();
    const bool ok = (*sok != 0);

    // ---- build warped-estimate tile (le,re,lv,rv) per halo slot ----
    for (int i = tid; i < NSTAGE; i += 256) {
        int sx = i % (TX + 2);
        int sy = i / (TX + 2);
        int x = min(max(xo0 - 1 + sx, 0), w - 1);
        float dl = sdl[sy * SW + (x - lx0)];
        float dr = sdr[sy * SW + (x - rx0)];
        float xb = (float)x * invWm1;
        int i0L, i1L, i0R, i1R;
        float w0L, w1L, w0R, w1R;
        warp_coeffs((xb - dl) * Wm1, w, i0L, i1L, w0L, w1L);
        warp_coeffs((xb + dr) * Wm1, w, i0R, i1R, w0R, w1R);
        if (ok) {
            int a0 = i0L - rx0, a1 = i1L - rx0;
            int b0 = i0R - lx0, b1 = i1R - lx0;
            int xl = x - lx0, xr = x - rx0;
#pragma unroll
            for (int c = 0; c < 3; ++c) {
                const float* R = sRp + (c * NROWS + sy) * SW;
                const float* L = sLp + (c * NROWS + sy) * SW;
                float le = R[a0] * w0L + R[a1] * w1L;
                float re = L[b0] * w0R + L[b1] * w1R;
                simg[c * NSTAGE + i] = make_float4(le, re, L[xl], R[xr]);
            }
        } else {
            int y = min(max(gy0 + sy, 0), h - 1);
            int rowoff = y * w;
#pragma unroll
            for (int c = 0; c < 3; ++c) {
                int co = c * chs + rowoff;
                float le = rimg[co + i0L] * w0L + rimg[co + i1L] * w1L;
                float re = limg[co + i0R] * w0R + limg[co + i1R] * w1R;
                simg[c * NSTAGE + i] = make_float4(le, re, limg[co + x], rimg[co + x]);
            }
        }
    }
    __syncthreads();

    float sums[8] = {0.f, 0.f, 0.f, 0.f, 0.f, 0.f, 0.f, 0.f};
    const int tx = tid % TX, ty = tid / TX;
    const int x = xo0 + tx, y = yo0 + ty;
    if (x < w && y < h) {
        const int s = (ty + 1) * (TX + 2) + (tx + 1);
        const int kdl = (ty + 1) * SW + (tx + 1);
        const int kdr = kdl + MAXD;                 // x - rx0 = tx+1+MAXD
        float dl = sdl[kdl];
        float dr = sdr[kdr];
#pragma unroll
        for (int c = 0; c < 3; ++c) {
            float4 v = simg[c * NSTAGE + s];
            float2 d = f2abs(make_float2(v.x, v.y) - make_float2(v.z, v.w));
            sums[0] += d.x;
            sums[1] += d.y;
        }
        // LR consistency gathers
        {
            float xb = (float)x * invWm1;
            int i0, i1; float w0, w1;
            warp_coeffs((xb - dl) * Wm1, w, i0, i1, w0, w1);
            float rl;
            if (ok) {
                rl = sdr[(ty + 1) * SW + (i0 - rx0)] * w0 +
                     sdr[(ty + 1) * SW + (i1 - rx0)] * w1;
            } else {
                const float* drr = dr_base + y * w;
                rl = drr[i0] * w0 + drr[i1] * w1;
            }
            sums[2] += fabsf(rl - dl);
            warp_coeffs((xb + dr) * Wm1, w, i0, i1, w0, w1);
            float lr;
            if (ok) {
                lr = sdl[(ty + 1) * SW + (i0 - lx0)] * w0 +
                     sdl[(ty + 1) * SW + (i1 - lx0)] * w1;
            } else {
                const float* dlr = dl_base + y * w;
                lr = dlr[i0] * w0 + dlr[i1] * w1;
            }
            sums[3] += fabsf(lr - dr);
        }
        const float third = 1.f / 3.f;
        if (x < w - 1) {
            float dlx = sdl[kdl + 1], drx = sdr[kdr + 1];
            float2 alr = f2(0.f);
#pragma unroll
            for (int c = 0; c < 3; ++c) {
                float4 v = simg[c * NSTAGE + s];
                float4 v1 = simg[c * NSTAGE + s + 1];
                alr = alr + f2abs(make_float2(v.z, v.w) - make_float2(v1.z, v1.w));
            }
            sums[4] += fabsf((dl - dlx) * __expf(-alr.x * third)) +
                       fabsf((dr - drx) * __expf(-alr.y * third));
        }
        if (y < h - 1) {
            float dly = sdl[kdl + SW], dry = sdr[kdr + SW];
            float2 alr = f2(0.f);
#pragma unroll
            for (int c = 0; c < 3; ++c) {
                float4 v = simg[c * NSTAGE + s];
                float4 v1 = simg[c * NSTAGE + s + (TX + 2)];
                alr = alr + f2abs(make_float2(v.z, v.w) - make_float2(v1.z, v1.w));
            }
            sums[5] += fabsf((dl - dly) * __expf(-alr.x * third)) +
                       fabsf((dr - dry) * __expf(-alr.y * third));
        }
        if (x >= 1 && x <= w - 2 && y >= 1 && y <= h - 2) {
            const float2 inv9 = f2(1.f / 9.f);
            const float2 c1 = f2(C1F), c2 = f2(C2F);
            const float2 two = f2(2.f), one = f2(1.f), half_ = f2(0.5f);
#pragma unroll 1
            for (int c = 0; c < 3; ++c) {
                float2 sX = f2(0.f), sY = f2(0.f);
                float2 sXX = f2(0.f), sYY = f2(0.f), sXY = f2(0.f);
#pragma unroll
                for (int dy = 0; dy < 3; ++dy) {
#pragma unroll
                    for (int dx = 0; dx < 3; ++dx) {
                        float4 v = simg[c * NSTAGE + (ty + dy) * (TX + 2) + (tx + dx)];
                        float2 a = make_float2(v.x, v.y);
                        float2 bb = make_float2(v.z, v.w);
                        sX = sX + a;
                        sY = sY + bb;
                        sXX = sXX + a * a;
                        sYY = sYY + bb * bb;
                        sXY = sXY + a * bb;
                    }
                }
                float2 mx = sX * inv9, my = sY * inv9;
                float2 vx = sXX * inv9 - mx * mx;
                float2 vy = sYY * inv9 - my * my;
                float2 vxy = sXY * inv9 - mx * my;
                float2 num = (two * mx * my + c1) * (two * vxy + c2);
                float2 den = (mx * mx + my * my + c1) * (vx + vy + c2);
                float2 ss = make_float2(num.x * __builtin_amdgcn_rcpf(den.x),
                                        num.y * __builtin_amdgcn_rcpf(den.y));
                float2 v = (one - ss) * half_;
                sums[6] += fminf(fmaxf(v.x, 0.f), 1.f);
                sums[7] += fminf(fmaxf(v.y, 0.f), 1.f);
            }
        }
    }
    block_acc<8>(sums, acc);
}

#define SW0 144   // TX + 77 + 3   (scale 0: maxd=77)
#define SWB 106   // TX + 39 + 3   (scale 1: maxd=39; covers scales 2,3)

// ---- Kernel A: scale-0 fused tiles + pyramid resize (round-0 structure) ----
__global__ void __launch_bounds__(256, 3)
k_fused0_resize(ScaleArgs s0, float* __restrict__ accbase,
                const float* __restrict__ left, const float* __restrict__ right,
                float* __restrict__ lo1, float* __restrict__ ro1,
                float* __restrict__ lo2, float* __restrict__ ro2,
                float* __restrict__ lo3, float* __restrict__ ro3,
                int B, int H, int W,
                int nFusedBlocks, long long n1, long long n2, long long n3) {
    __shared__ float4 simg[3 * NSTAGE];
    __shared__ float sL[3 * NROWS * SW0];
    __shared__ float sR[3 * NROWS * SW0];
    __shared__ float sdl[NROWS * SW0];
    __shared__ float sdr[NROWS * SW0];
    __shared__ int sok;

    if ((int)blockIdx.x < nFusedBlocks) {
        int t = xcd_swz((int)blockIdx.x, nFusedBlocks);
        fused_tile<SW0>(s0, t, accbase, simg, sL, sR, sdl, sdr, &sok);
        return;
    }
    long long idx = (long long)(blockIdx.x - nFusedBlocks) * blockDim.x + threadIdx.x;
    int oh, ow;
    float* lo;
    float* ro;
    if (idx < n1) {
        oh = H / 2; ow = W / 2; lo = lo1; ro = ro1;
    } else if (idx < n1 + n2) {
        idx -= n1; oh = H / 4; ow = W / 4; lo = lo2; ro = ro2;
    } else if (idx < n1 + n2 + n3) {
        idx -= n1 + n2; oh = H / 8; ow = W / 8; lo = lo3; ro = ro3;
    } else {
        return;
    }
    long long half = (long long)B * 3 * oh * ow;
    const float* src = left;
    float* dst = lo;
    if (idx >= half) { src = right; dst = ro; idx -= half; }
    int x = (int)(idx % ow);
    long long t = idx / ow;
    int y = (int)(t % oh);
    t /= oh;
    int c = (int)(t % 3);
    int b = (int)(t / 3);
    float sy = (float)(H - 1) / (float)(oh - 1);
    float sx = (float)(W - 1) / (float)(ow - 1);
    float fy = y * sy;
    float fx = x * sx;
    int y0 = (int)floorf(fy); float wy = fy - (float)y0;
    int x0 = (int)floorf(fx); float wx = fx - (float)x0;
    int y1 = min(y0 + 1, H - 1); y0 = min(y0, H - 1);
    int x1 = min(x0 + 1, W - 1); x0 = min(x0, W - 1);
    const float* p = src + ((long long)b * 3 + c) * H * W;
    float a00 = p[(long long)y0 * W + x0];
    float a10 = p[(long long)y1 * W + x0];
    float a01 = p[(long long)y0 * W + x1];
    float a11 = p[(long long)y1 * W + x1];
    float r0 = a00 * (1.f - wy) + a10 * wy;
    float r1 = a01 * (1.f - wy) + a11 * wy;
    dst[(((long long)b * 3 + c) * oh + y) * ow + x] = r0 * (1.f - wx) + r1 * wx;
}

// ---- Kernel B: scales 1-3 fused (reads pyramid) ----
__global__ void __launch_bounds__(256, 4)
k_fused_small(ScaleArgs s1, ScaleArgs s2, ScaleArgs s3,
              float* __restrict__ accbase) {
    __shared__ float4 simg[3 * NSTAGE];
    __shared__ float sL[3 * NROWS * SWB];
    __shared__ float sR[3 * NROWS * SWB];
    __shared__ float sdl[NROWS * SWB];
    __shared__ float sdr[NROWS * SWB];
    __shared__ int sok;

    ScaleArgs sa;
    {
        int blk = (int)blockIdx.x;
        if (blk >= s3.blk0)      sa = s3;
        else if (blk >= s2.blk0) sa = s2;
        else                     sa = s1;
    }
    int t = xcd_swz((int)blockIdx.x - sa.blk0, sa.ntiles);
    fused_tile<SWB>(sa, t, accbase, simg, sL, sR, sdl, sdr, &sok);
}

__global__ void k_final(const float* __restrict__ acc, float* __restrict__ out,
                        int B, int H, int W) {
    if (threadIdx.x != 0 || blockIdx.x != 0) return;
    float img = 0.f, lr = 0.f, sm = 0.f;
    for (int i = 0; i < 4; ++i) {
        int r = 1 << i;
        int h = H / r, w = W / r;
        const float* a = acc + i * 8;
        float Nl1 = (float)B * 3.f * (float)h * (float)w;
        float Nss = (float)B * 3.f * (float)(h - 2) * (float)(w - 2);
        float Nlr = (float)B * (float)h * (float)w;
        float Nsx = (float)B * (float)h * (float)(w - 1);
        float Nsy = (float)B * (float)(h - 1) * (float)w;
        img += 0.5f * (a[6] / Nss) + 0.5f * (a[0] / Nl1)
             + 0.5f * (a[7] / Nss) + 0.5f * (a[1] / Nl1);
        lr += a[2] / Nlr + a[3] / Nlr;
        sm += (a[4] / Nsx + a[5] / Nsy) / (float)r;
    }
    out[0] = img + 0.1f * sm + 1.0f * lr;
}

extern "C" void kernel_launch(void* const* d_in, const int* in_sizes, int n_in,
                              void* d_out, int out_size, void* d_ws, size_t ws_size,
                              hipStream_t stream) {
    const int B = 16, H = 384, W = 768;
    const float* disp[4] = {(const float*)d_in[0], (const float*)d_in[1],
                            (const float*)d_in[2], (const float*)d_in[3]};
    const float* left = (const float*)d_in[4];
    const float* right = (const float*)d_in[5];
    float* out = (float*)d_out;

    float* acc = (float*)d_ws;
    float* pyr = acc + 256;
    long long sz1 = (long long)B * 3 * (H / 2) * (W / 2);
    long long sz2 = (long long)B * 3 * (H / 4) * (W / 4);
    long long sz3 = (long long)B * 3 * (H / 8) * (W / 8);
    float* lp1 = pyr;
    float* rp1 = lp1 + sz1;
    float* lp2 = rp1 + sz1;
    float* rp2 = lp2 + sz2;
    float* lp3 = rp2 + sz2;
    float* rp3 = lp3 + sz3;

    const int TB = 256;
    const float* lp[4] = {left, lp1, lp2, lp3};
    const float* rp[4] = {right, rp1, rp2, rp3};
    const int maxd_tab[4] = {77, 39, 20, 10};
    ScaleArgs sa[4];
    for (int i = 0; i < 4; ++i) {
        int r = 1 << i;
        int h = H / r, w = W / r;
        sa[i].disp = disp[i];
        sa[i].lp = lp[i];
        sa[i].rp = rp[i];
        sa[i].h = h;
        sa[i].w = w;
        sa[i].nx = (w + TX - 1) / TX;
        sa[i].ny = (h + TY - 1) / TY;
        sa[i].accoff = i * 8;
        sa[i].ntiles = sa[i].nx * sa[i].ny * B;
        sa[i].blk0 = 0;
        sa[i].maxd = maxd_tab[i];
        sa[i].dmax = (float)maxd_tab[i] / (float)(w - 1);
    }

    hipLaunchKernelGGL(k_zero, dim3(1), dim3(64), 0, stream, acc);

    // Kernel A: scale-0 fused + all resize work
    {
        int nFused = sa[0].ntiles;                       // 12*96*16 = 18432
        long long n1 = 2 * sz1, n2 = 2 * sz2, n3 = 2 * sz3;
        long long nrElem = n1 + n2 + n3;
        int nResize = (int)((nrElem + TB - 1) / TB);
        hipLaunchKernelGGL(k_fused0_resize, dim3((unsigned)(nFused + nResize)), dim3(TB), 0, stream,
                           sa[0], acc, left, right, lp1, rp1, lp2, rp2, lp3, rp3,
                           B, H, W, nFused, n1, n2, n3);
    }

    // Kernel B: scales 1-3 fused
    {
        int b1 = sa[1].ntiles;
        int b2 = sa[2].ntiles;
        int b3 = sa[3].ntiles;
        sa[1].blk0 = 0;
        sa[2].blk0 = b1;
        sa[3].blk0 = b1 + b2;
        hipLaunchKernelGGL(k_fused_small, dim3((unsigned)(b1 + b2 + b3)), dim3(TB), 0, stream,
                           sa[1], sa[2], sa[3], acc);
    }
    hipLaunchKernelGGL(k_final, dim3(1), dim3(64), 0, stream, acc, out, B, H, W);
}

// Round 4
// 518.068 us; speedup vs baseline: 3.4713x; 1.4133x over previous
//
#include <hip/hip_runtime.h>
#include <math.h>

#define C1F 1.0e-4f   // 0.01^2
#define C2F 9.0e-4f   // 0.03^2
#define TX 64
#define TY 4
#define NROWS (TY + 2)                       // 6
#define NSTAGE ((TY + 2) * (TX + 2))         // 396
#define LPAD 4

// acc layout: per scale i (0..3), base = i*8
//  +0: sum |left_est - lpy|      +1: sum |right_est - rpy|
//  +2: sum |rl_disp - dl|        +3: sum |lr_disp - dr|
//  +4: sum x-grad smooth (dl+dr) +5: sum y-grad smooth (dl+dr)
//  +6: sum ssim_l (clipped)      +7: sum ssim_r

struct ScaleArgs {
    const float* disp;   // scale-res disparity
    const float* lp;     // scale-res left image (pyramid for i>0)
    const float* rp;     // scale-res right image
    int h, w, nx, ny, blk0, accoff, ntiles;
    float dmax;          // fast-path disparity bound (reach/(w-1))
};

__device__ __forceinline__ float2 f2(float v) { return make_float2(v, v); }

__device__ __forceinline__ void warp_coeffs(float px, int W, int& i0, int& i1,
                                            float& w0, float& w1) {
    float x0f = floorf(px);
    float f = px - x0f;
    int x0i = (int)x0f;
    int x1i = x0i + 1;
    float v0 = (x0i >= 0 && x0i < W) ? 1.f : 0.f;
    float v1 = (x1i >= 0 && x1i < W) ? 1.f : 0.f;
    i0 = min(max(x0i, 0), W - 1);
    i1 = min(max(x1i, 0), W - 1);
    w0 = v0 * (1.f - f);
    w1 = v1 * f;
}

template<int N>
__device__ __forceinline__ void block_acc(const float* vals, float* gacc) {
    __shared__ float sacc[N];
    if (threadIdx.x < N) sacc[threadIdx.x] = 0.f;
    __syncthreads();
#pragma unroll
    for (int k = 0; k < N; ++k) {
        float v = vals[k];
#pragma unroll
        for (int off = 32; off > 0; off >>= 1) v += __shfl_down(v, off, 64);
        if ((threadIdx.x & 63) == 0) atomicAdd(&sacc[k], v);
    }
    __syncthreads();
    if (threadIdx.x < N) atomicAdd(&gacc[threadIdx.x], sacc[threadIdx.x]);
}

// Bijective XCD-chunked swizzle (m204 form).
__device__ __forceinline__ int xcd_swz(int orig, int n) {
    int q = n >> 3, r = n & 7;
    int x = orig & 7;
    int base = (x < r) ? x * (q + 1) : r * (q + 1) + (x - r) * q;
    return base + (orig >> 3);
}

__global__ void k_zero(float* acc) {
    if (threadIdx.x < 64) acc[threadIdx.x] = 0.f;
}

__device__ __forceinline__ bool rng_ok(float v, float dmax) {
    return (v >= 0.f) && (v <= dmax);   // NaN -> false
}

// ---- fused loss tile with LDS-staged gather stripes ----
// Left-side stripe (left img + dl): base lx0 = xo0-LPAD, covers direct reads
// [xo0-1, xo0+65] and rightward gathers up to +reach.  Right-side stripe
// (right img + dr): base rx0 = xo0-RPAD, covers leftward gathers down to
// -reach.  All bases multiple of 4 -> float4 staging.  Per-tile disparity
// range check selects the LDS fast path; fallback = exact global gathers.
template<int SW, int RPAD>
__device__ void fused_tile(const ScaleArgs& sa, int t, float* __restrict__ accbase,
                           float* __restrict__ sL, float* __restrict__ sR,
                           float* __restrict__ sdl, float* __restrict__ sdr,
                           float2* __restrict__ simg, int* __restrict__ sok) {
    constexpr int SW4 = SW / 4;
    const int h = sa.h, w = sa.w;
    float* acc = accbase + sa.accoff;

    const int tileX = t % sa.nx;
    int t2 = t / sa.nx;
    const int tileY = t2 % sa.ny;
    const int b = t2 / sa.ny;

    const int xo0 = tileX * TX, yo0 = tileY * TY;
    const int tid = threadIdx.x;
    const float Wm1 = (float)(w - 1);
    const float invWm1 = 1.f / Wm1;
    const int chs = h * w;
    const int lx0 = xo0 - LPAD;
    const int rx0 = xo0 - RPAD;
    const int gy0 = yo0 - 1;
    const float dmax = sa.dmax;

    const float* __restrict__ dl_base = sa.disp + (b * 2 + 0) * chs;
    const float* __restrict__ dr_base = sa.disp + (b * 2 + 1) * chs;
    const float* __restrict__ limg = sa.lp + b * 3 * chs;
    const float* __restrict__ rimg = sa.rp + b * 3 * chs;

    if (tid == 0) *sok = 1;
    __syncthreads();

    bool bad = false;
    const bool xint = (rx0 >= 0) && (lx0 + SW <= w);
    if (xint) {
        // ---- vectorized staging: (row, k4) shared by all 8 arrays ----
        for (int i = tid; i < NROWS * SW4; i += 256) {
            int r = i / SW4, k4 = i - r * SW4;
            int y = min(max(gy0 + r, 0), h - 1);
            int goL = y * w + lx0 + 4 * k4;
            int goR = y * w + rx0 + 4 * k4;
            int so = r * SW + 4 * k4;
#pragma unroll
            for (int c = 0; c < 3; ++c) {
                *(float4*)(sL + c * (NROWS * SW) + so) =
                    *(const float4*)(limg + c * chs + goL);
                *(float4*)(sR + c * (NROWS * SW) + so) =
                    *(const float4*)(rimg + c * chs + goR);
            }
            float4 vdl = *(const float4*)(dl_base + goL);
            float4 vdr = *(const float4*)(dr_base + goR);
            *(float4*)(sdl + so) = vdl;
            *(float4*)(sdr + so) = vdr;
            bad = bad || !rng_ok(vdl.x, dmax) || !rng_ok(vdl.y, dmax) ||
                         !rng_ok(vdl.z, dmax) || !rng_ok(vdl.w, dmax) ||
                         !rng_ok(vdr.x, dmax) || !rng_ok(vdr.y, dmax) ||
                         !rng_ok(vdr.z, dmax) || !rng_ok(vdr.w, dmax);
        }
    } else {
        // ---- scalar clamped staging (x-edge tiles only) ----
        for (int i = tid; i < NROWS * SW; i += 256) {
            int r = i / SW, k = i - r * SW;
            int y = min(max(gy0 + r, 0), h - 1);
            int xl = min(max(lx0 + k, 0), w - 1);
            int xr = min(max(rx0 + k, 0), w - 1);
            int yw = y * w;
#pragma unroll
            for (int c = 0; c < 3; ++c) {
                sL[c * (NROWS * SW) + i] = limg[c * chs + yw + xl];
                sR[c * (NROWS * SW) + i] = rimg[c * chs + yw + xr];
            }
            float vdl = dl_base[yw + xl];
            float vdr = dr_base[yw + xr];
            sdl[i] = vdl;
            sdr[i] = vdr;
            bad = bad || !rng_ok(vdl, dmax) || !rng_ok(vdr, dmax);
        }
    }
    if (bad) *sok = 0;
    __syncthreads();
    const bool ok = (*sok != 0);

    // ---- build warped-estimate tile (le,re) per halo slot ----
    for (int i = tid; i < NSTAGE; i += 256) {
        int sx = i % (TX + 2);
        int sy = i / (TX + 2);
        int x = min(max(xo0 - 1 + sx, 0), w - 1);
        float dl = sdl[sy * SW + (x - lx0)];
        float dr = sdr[sy * SW + (x - rx0)];
        float xb = (float)x * invWm1;
        int i0L, i1L, i0R, i1R;
        float w0L, w1L, w0R, w1R;
        warp_coeffs((xb - dl) * Wm1, w, i0L, i1L, w0L, w1L);
        warp_coeffs((xb + dr) * Wm1, w, i0R, i1R, w0R, w1R);
        if (ok) {
            int a0 = i0L - rx0, a1 = i1L - rx0;
            int b0 = i0R - lx0, b1 = i1R - lx0;
#pragma unroll
            for (int c = 0; c < 3; ++c) {
                const float* R = sR + (c * NROWS + sy) * SW;
                const float* L = sL + (c * NROWS + sy) * SW;
                simg[c * NSTAGE + i] =
                    make_float2(R[a0] * w0L + R[a1] * w1L,
                                L[b0] * w0R + L[b1] * w1R);
            }
        } else {
            int y = min(max(gy0 + sy, 0), h - 1);
            int rowoff = y * w;
#pragma unroll
            for (int c = 0; c < 3; ++c) {
                int co = c * chs + rowoff;
                simg[c * NSTAGE + i] =
                    make_float2(rimg[co + i0L] * w0L + rimg[co + i1L] * w1L,
                                limg[co + i0R] * w0R + limg[co + i1R] * w1R);
            }
        }
    }
    __syncthreads();

    float sums[8] = {0.f, 0.f, 0.f, 0.f, 0.f, 0.f, 0.f, 0.f};
    const int tx = tid & (TX - 1), ty = tid >> 6;
    const int x = xo0 + tx, y = yo0 + ty;
    if (x < w && y < h) {
        const int s = (ty + 1) * (TX + 2) + tx + 1;
        const int rowd = (ty + 1) * SW;
        const int kL = tx + LPAD;       // x - lx0
        const int kR = tx + RPAD;       // x - rx0
        float dl = sdl[rowd + kL];
        float dr = sdr[rowd + kR];
#pragma unroll
        for (int c = 0; c < 3; ++c) {
            float2 e = simg[c * NSTAGE + s];
            float lv = sL[(c * NROWS + ty + 1) * SW + kL];
            float rv = sR[(c * NROWS + ty + 1) * SW + kR];
            sums[0] += fabsf(e.x - lv);
            sums[1] += fabsf(e.y - rv);
        }
        // LR consistency gathers
        {
            float xb = (float)x * invWm1;
            int i0, i1; float w0, w1;
            warp_coeffs((xb - dl) * Wm1, w, i0, i1, w0, w1);
            float rl;
            if (ok) {
                rl = sdr[rowd + (i0 - rx0)] * w0 + sdr[rowd + (i1 - rx0)] * w1;
            } else {
                const float* drr = dr_base + y * w;
                rl = drr[i0] * w0 + drr[i1] * w1;
            }
            sums[2] += fabsf(rl - dl);
            warp_coeffs((xb + dr) * Wm1, w, i0, i1, w0, w1);
            float lr;
            if (ok) {
                lr = sdl[rowd + (i0 - lx0)] * w0 + sdl[rowd + (i1 - lx0)] * w1;
            } else {
                const float* dlr = dl_base + y * w;
                lr = dlr[i0] * w0 + dlr[i1] * w1;
            }
            sums[3] += fabsf(lr - dr);
        }
        const float third = 1.f / 3.f;
        if (x < w - 1) {
            float dlx = sdl[rowd + kL + 1], drx = sdr[rowd + kR + 1];
            float ax = 0.f, ay = 0.f;
#pragma unroll
            for (int c = 0; c < 3; ++c) {
                const float* Lr = sL + (c * NROWS + ty + 1) * SW;
                const float* Rr = sR + (c * NROWS + ty + 1) * SW;
                ax += fabsf(Lr[kL] - Lr[kL + 1]);
                ay += fabsf(Rr[kR] - Rr[kR + 1]);
            }
            sums[4] += fabsf(dl - dlx) * __expf(-ax * third) +
                       fabsf(dr - drx) * __expf(-ay * third);
        }
        if (y < h - 1) {
            float dly = sdl[rowd + SW + kL], dry = sdr[rowd + SW + kR];
            float ax = 0.f, ay = 0.f;
#pragma unroll
            for (int c = 0; c < 3; ++c) {
                const float* Lr0 = sL + (c * NROWS + ty + 1) * SW;
                const float* Lr1 = Lr0 + SW;
                const float* Rr0 = sR + (c * NROWS + ty + 1) * SW;
                const float* Rr1 = Rr0 + SW;
                ax += fabsf(Lr0[kL] - Lr1[kL]);
                ay += fabsf(Rr0[kR] - Rr1[kR]);
            }
            sums[5] += fabsf(dl - dly) * __expf(-ax * third) +
                       fabsf(dr - dry) * __expf(-ay * third);
        }
        if (x >= 1 && x <= w - 2 && y >= 1 && y <= h - 2) {
            const float2 inv9 = f2(1.f / 9.f);
            const float2 c1 = f2(C1F), c2 = f2(C2F);
            const float2 two = f2(2.f), one = f2(1.f), half_ = f2(0.5f);
#pragma unroll 1
            for (int c = 0; c < 3; ++c) {
                float2 sX = f2(0.f), sY = f2(0.f);
                float2 sXX = f2(0.f), sYY = f2(0.f), sXY = f2(0.f);
#pragma unroll
                for (int dy = 0; dy < 3; ++dy) {
                    const float2* eS = simg + c * NSTAGE + (ty + dy) * (TX + 2);
                    const float* Lr = sL + (c * NROWS + ty + dy) * SW;
                    const float* Rr = sR + (c * NROWS + ty + dy) * SW;
#pragma unroll
                    for (int dx = 0; dx < 3; ++dx) {
                        float2 a = eS[tx + dx];
                        float lv = Lr[tx + dx + LPAD - 1];
                        float rv = Rr[tx + dx + RPAD - 1];
                        sX.x += a.x;  sX.y += a.y;
                        sY.x += lv;   sY.y += rv;
                        sXX.x += a.x * a.x;  sXX.y += a.y * a.y;
                        sYY.x += lv * lv;    sYY.y += rv * rv;
                        sXY.x += a.x * lv;   sXY.y += a.y * rv;
                    }
                }
                float2 mx = make_float2(sX.x * inv9.x, sX.y * inv9.y);
                float2 my = make_float2(sY.x * inv9.x, sY.y * inv9.y);
                float2 vx = make_float2(sXX.x * inv9.x - mx.x * mx.x,
                                        sXX.y * inv9.y - mx.y * mx.y);
                float2 vy = make_float2(sYY.x * inv9.x - my.x * my.x,
                                        sYY.y * inv9.y - my.y * my.y);
                float2 vxy = make_float2(sXY.x * inv9.x - mx.x * my.x,
                                         sXY.y * inv9.y - mx.y * my.y);
                float2 num = make_float2((two.x * mx.x * my.x + c1.x) * (two.x * vxy.x + c2.x),
                                         (two.y * mx.y * my.y + c1.y) * (two.y * vxy.y + c2.y));
                float2 den = make_float2((mx.x * mx.x + my.x * my.x + c1.x) * (vx.x + vy.x + c2.x),
                                         (mx.y * mx.y + my.y * my.y + c1.y) * (vx.y + vy.y + c2.y));
                float2 ss = make_float2(num.x * __builtin_amdgcn_rcpf(den.x),
                                        num.y * __builtin_amdgcn_rcpf(den.y));
                float2 v = make_float2((one.x - ss.x) * half_.x,
                                       (one.y - ss.y) * half_.y);
                sums[6] += fminf(fmaxf(v.x, 0.f), 1.f);
                sums[7] += fminf(fmaxf(v.y, 0.f), 1.f);
            }
        }
    }
    block_acc<8>(sums, acc);
}

#define SW0 152   // lx0=xo0-4, rx0=xo0-84, reach 78 px (covers 0.1*767=76.7)
#define RP0 84
#define SWB 112   // lx0=xo0-4, rx0=xo0-44, reach 40 px (covers 0.1*(w-1)<=38.3)
#define RPB 44

// ---- Kernel A: scale-0 fused tiles + pyramid resize ----
__global__ void __launch_bounds__(256, 4)
k_fused0_resize(ScaleArgs s0, float* __restrict__ accbase,
                const float* __restrict__ left, const float* __restrict__ right,
                float* __restrict__ lo1, float* __restrict__ ro1,
                float* __restrict__ lo2, float* __restrict__ ro2,
                float* __restrict__ lo3, float* __restrict__ ro3,
                int B, int H, int W,
                int nFusedBlocks, long long n1, long long n2, long long n3) {
    __shared__ __align__(16) float sL[3 * NROWS * SW0];
    __shared__ __align__(16) float sR[3 * NROWS * SW0];
    __shared__ __align__(16) float sdl[NROWS * SW0];
    __shared__ __align__(16) float sdr[NROWS * SW0];
    __shared__ __align__(16) float2 simg[3 * NSTAGE];
    __shared__ int sok;

    if ((int)blockIdx.x < nFusedBlocks) {
        int t = xcd_swz((int)blockIdx.x, nFusedBlocks);
        fused_tile<SW0, RP0>(s0, t, accbase, sL, sR, sdl, sdr, simg, &sok);
        return;
    }
    long long idx = (long long)(blockIdx.x - nFusedBlocks) * blockDim.x + threadIdx.x;
    int oh, ow;
    float* lo;
    float* ro;
    if (idx < n1) {
        oh = H / 2; ow = W / 2; lo = lo1; ro = ro1;
    } else if (idx < n1 + n2) {
        idx -= n1; oh = H / 4; ow = W / 4; lo = lo2; ro = ro2;
    } else if (idx < n1 + n2 + n3) {
        idx -= n1 + n2; oh = H / 8; ow = W / 8; lo = lo3; ro = ro3;
    } else {
        return;
    }
    long long half = (long long)B * 3 * oh * ow;
    const float* src = left;
    float* dst = lo;
    if (idx >= half) { src = right; dst = ro; idx -= half; }
    int x = (int)(idx % ow);
    long long t = idx / ow;
    int y = (int)(t % oh);
    t /= oh;
    int c = (int)(t % 3);
    int b = (int)(t / 3);
    float sy = (float)(H - 1) / (float)(oh - 1);
    float sx = (float)(W - 1) / (float)(ow - 1);
    float fy = y * sy;
    float fx = x * sx;
    int y0 = (int)floorf(fy); float wy = fy - (float)y0;
    int x0 = (int)floorf(fx); float wx = fx - (float)x0;
    int y1 = min(y0 + 1, H - 1); y0 = min(y0, H - 1);
    int x1 = min(x0 + 1, W - 1); x0 = min(x0, W - 1);
    const float* p = src + ((long long)b * 3 + c) * H * W;
    float a00 = p[(long long)y0 * W + x0];
    float a10 = p[(long long)y1 * W + x0];
    float a01 = p[(long long)y0 * W + x1];
    float a11 = p[(long long)y1 * W + x1];
    float r0 = a00 * (1.f - wy) + a10 * wy;
    float r1 = a01 * (1.f - wy) + a11 * wy;
    dst[(((long long)b * 3 + c) * oh + y) * ow + x] = r0 * (1.f - wx) + r1 * wx;
}

// ---- Kernel B: scales 1-3 fused (reads pyramid) ----
__global__ void __launch_bounds__(256, 5)
k_fused_small(ScaleArgs s1, ScaleArgs s2, ScaleArgs s3,
              float* __restrict__ accbase) {
    __shared__ __align__(16) float sL[3 * NROWS * SWB];
    __shared__ __align__(16) float sR[3 * NROWS * SWB];
    __shared__ __align__(16) float sdl[NROWS * SWB];
    __shared__ __align__(16) float sdr[NROWS * SWB];
    __shared__ __align__(16) float2 simg[3 * NSTAGE];
    __shared__ int sok;

    ScaleArgs sa;
    {
        int blk = (int)blockIdx.x;
        if (blk >= s3.blk0)      sa = s3;
        else if (blk >= s2.blk0) sa = s2;
        else                     sa = s1;
    }
    int t = xcd_swz((int)blockIdx.x - sa.blk0, sa.ntiles);
    fused_tile<SWB, RPB>(sa, t, accbase, sL, sR, sdl, sdr, simg, &sok);
}

__global__ void k_final(const float* __restrict__ acc, float* __restrict__ out,
                        int B, int H, int W) {
    if (threadIdx.x != 0 || blockIdx.x != 0) return;
    float img = 0.f, lr = 0.f, sm = 0.f;
    for (int i = 0; i < 4; ++i) {
        int r = 1 << i;
        int h = H / r, w = W / r;
        const float* a = acc + i * 8;
        float Nl1 = (float)B * 3.f * (float)h * (float)w;
        float Nss = (float)B * 3.f * (float)(h - 2) * (float)(w - 2);
        float Nlr = (float)B * (float)h * (float)w;
        float Nsx = (float)B * (float)h * (float)(w - 1);
        float Nsy = (float)B * (float)(h - 1) * (float)w;
        img += 0.5f * (a[6] / Nss) + 0.5f * (a[0] / Nl1)
             + 0.5f * (a[7] / Nss) + 0.5f * (a[1] / Nl1);
        lr += a[2] / Nlr + a[3] / Nlr;
        sm += (a[4] / Nsx + a[5] / Nsy) / (float)r;
    }
    out[0] = img + 0.1f * sm + 1.0f * lr;
}

extern "C" void kernel_launch(void* const* d_in, const int* in_sizes, int n_in,
                              void* d_out, int out_size, void* d_ws, size_t ws_size,
                              hipStream_t stream) {
    const int B = 16, H = 384, W = 768;
    const float* disp[4] = {(const float*)d_in[0], (const float*)d_in[1],
                            (const float*)d_in[2], (const float*)d_in[3]};
    const float* left = (const float*)d_in[4];
    const float* right = (const float*)d_in[5];
    float* out = (float*)d_out;

    float* acc = (float*)d_ws;
    float* pyr = acc + 256;
    long long sz1 = (long long)B * 3 * (H / 2) * (W / 2);
    long long sz2 = (long long)B * 3 * (H / 4) * (W / 4);
    long long sz3 = (long long)B * 3 * (H / 8) * (W / 8);
    float* lp1 = pyr;
    float* rp1 = lp1 + sz1;
    float* lp2 = rp1 + sz1;
    float* rp2 = lp2 + sz2;
    float* lp3 = rp2 + sz2;
    float* rp3 = lp3 + sz3;

    const int TB = 256;
    const float* lp[4] = {left, lp1, lp2, lp3};
    const float* rp[4] = {right, rp1, rp2, rp3};
    // fast-path reach in px: scale0 78 (stripe SW0/RP0), scales1-3 40 (SWB/RPB)
    const float reach_tab[4] = {78.f, 40.f, 40.f, 40.f};
    ScaleArgs sa[4];
    for (int i = 0; i < 4; ++i) {
        int r = 1 << i;
        int h = H / r, w = W / r;
        sa[i].disp = disp[i];
        sa[i].lp = lp[i];
        sa[i].rp = rp[i];
        sa[i].h = h;
        sa[i].w = w;
        sa[i].nx = (w + TX - 1) / TX;
        sa[i].ny = (h + TY - 1) / TY;
        sa[i].accoff = i * 8;
        sa[i].ntiles = sa[i].nx * sa[i].ny * B;
        sa[i].blk0 = 0;
        sa[i].dmax = reach_tab[i] / (float)(w - 1);
    }

    hipLaunchKernelGGL(k_zero, dim3(1), dim3(64), 0, stream, acc);

    // Kernel A: scale-0 fused + all resize work
    {
        int nFused = sa[0].ntiles;
        long long n1 = 2 * sz1, n2 = 2 * sz2, n3 = 2 * sz3;
        long long nrElem = n1 + n2 + n3;
        int nResize = (int)((nrElem + TB - 1) / TB);
        hipLaunchKernelGGL(k_fused0_resize, dim3((unsigned)(nFused + nResize)), dim3(TB), 0, stream,
                           sa[0], acc, left, right, lp1, rp1, lp2, rp2, lp3, rp3,
                           B, H, W, nFused, n1, n2, n3);
    }

    // Kernel B: scales 1-3 fused
    {
        int b1 = sa[1].ntiles;
        int b2 = sa[2].ntiles;
        int b3 = sa[3].ntiles;
        sa[1].blk0 = 0;
        sa[2].blk0 = b1;
        sa[3].blk0 = b1 + b2;
        hipLaunchKernelGGL(k_fused_small, dim3((unsigned)(b1 + b2 + b3)), dim3(TB), 0, stream,
                           sa[1], sa[2], sa[3], acc);
    }
    hipLaunchKernelGGL(k_final, dim3(1), dim3(64), 0, stream, acc, out, B, H, W);
}